// Round 18
// baseline (109.324 us; speedup 1.0000x reference)
//
#include <hip/hip_runtime.h>
#include <hip/hip_bf16.h>
#include <math.h>

#define EPSN 1e-12f
typedef unsigned short ushort_t;

typedef float f32x4 __attribute__((ext_vector_type(4)));
typedef short s16x8 __attribute__((ext_vector_type(8)));
typedef unsigned short u16x8 __attribute__((ext_vector_type(8)));
typedef unsigned short u16x4 __attribute__((ext_vector_type(4)));

__device__ __forceinline__ void gload_lds16(const void* g, void* l) {
  __builtin_amdgcn_global_load_lds((const __attribute__((address_space(1))) void*)g,
                                   (__attribute__((address_space(3))) void*)l, 16, 0, 0);
}

__device__ __forceinline__ float bf2f(ushort_t u) {
  return __uint_as_float(((unsigned)u) << 16);
}

// ---------------- kpack2: Wgkx pack + gate/zero rows + bWg + {Wib row-major AND WibT}
//                  dual-write + stackedA pad + k0 ssq partials ----------------
__global__ void kpack2(const float* __restrict__ Wi, const float* __restrict__ Wgk,
                       const float* __restrict__ W_g, const float* __restrict__ b_inp,
                       const float* __restrict__ b_g, __hip_bfloat16* __restrict__ oWi,
                       __hip_bfloat16* __restrict__ oWx, ushort_t* __restrict__ oWibT,
                       float* __restrict__ bWg, const float* __restrict__ x,
                       float* __restrict__ ssq8) {
  int bid = blockIdx.x;
  int t = threadIdx.x;
  if (bid < 2048) {
    int i = (bid * 256 + t) * 4;
    float4 v = *(const float4*)(Wgk + i);
    oWx[i + 0] = __float2bfloat16(v.x);
    oWx[i + 1] = __float2bfloat16(v.y);
    oWx[i + 2] = __float2bfloat16(v.z);
    oWx[i + 3] = __float2bfloat16(v.w);
  } else if (bid < 2064) {
    int i = (bid - 2048) * 1024 + t * 4;  // 16 blocks: 8 gate rows
    float4 v = *(const float4*)(W_g + i);
    __hip_bfloat16* o = oWx + 1024 * 2048 + i;
    o[0] = __float2bfloat16(v.x);
    o[1] = __float2bfloat16(v.y);
    o[2] = __float2bfloat16(v.z);
    o[3] = __float2bfloat16(v.w);
  } else if (bid < 2304) {
    int i = (bid - 2064) * 1024 + t * 4;  // 240 blocks: 120 zero rows of Wgkx
    ushort_t* o = (ushort_t*)(oWx + 1032 * 2048) + i;
    *(u16x4*)o = (u16x4){0, 0, 0, 0};
  } else if (bid < 2312) {
    int j = bid - 2304;  // 0..7
    const float* row = W_g + (size_t)j * 2048;
    float s = 0.f;
    for (int c = t; c < 2048; c += 256) s = fmaf(b_inp[c], row[c], s);
    __shared__ float red[256];
    red[t] = s;
    __syncthreads();
    for (int o = 128; o > 0; o >>= 1) {
      if (t < o) red[t] += red[t + o];
      __syncthreads();
    }
    if (t == 0) bWg[j] = red[0] + b_g[j];
  } else if (bid < 2824) {
    // dual: Wib (row-major bf16) + WibT (transposed); 512 tiles 64x64, W_inp read ONCE
    int tt = bid - 2312;
    int cp0 = (tt >> 4) * 64;
    int c0 = (tt & 15) * 64;
    __shared__ ushort_t tile[64][72];
    int r = t >> 2, cs = (t & 3) * 16;
    const float* src = Wi + (size_t)(cp0 + r) * 1024 + c0 + cs;
#pragma unroll
    for (int j = 0; j < 16; j += 4) {
      float4 v = *(const float4*)(src + j);
      __hip_bfloat16 h0 = __float2bfloat16(v.x), h1 = __float2bfloat16(v.y);
      __hip_bfloat16 h2 = __float2bfloat16(v.z), h3 = __float2bfloat16(v.w);
      tile[r][cs + j + 0] = *(ushort_t*)&h0;
      tile[r][cs + j + 1] = *(ushort_t*)&h1;
      tile[r][cs + j + 2] = *(ushort_t*)&h2;
      tile[r][cs + j + 3] = *(ushort_t*)&h3;
    }
    {
      u16x8 w0 = *(const u16x8*)&tile[r][cs];
      u16x8 w1 = *(const u16x8*)&tile[r][cs + 8];
      ushort_t* dst = (ushort_t*)oWi + (size_t)(cp0 + r) * 1024 + c0 + cs;
      *(u16x8*)dst = w0;
      *(u16x8*)(dst + 8) = w1;
    }
    __syncthreads();
    int c = t >> 2, ms = (t & 3) * 16;
    u16x8 o0, o1;
#pragma unroll
    for (int j = 0; j < 8; ++j) o0[j] = tile[ms + j][c];
#pragma unroll
    for (int j = 0; j < 8; ++j) o1[j] = tile[ms + 8 + j][c];
    ushort_t* dst = oWibT + (size_t)(c0 + c) * 2048 + cp0 + ms;
    *(u16x8*)dst = o0;
    *(u16x8*)(dst + 8) = o1;
  } else if (bid < 2952) {
    // zero pad rows 3200-3327 of stackedA
    int i = (bid - 2824) * 1024 + t * 4;
    ushort_t* o = (ushort_t*)oWi + (size_t)3200 * 1024 + i;
    *(u16x4*)o = (u16x4){0, 0, 0, 0};
  } else {
    // fused k0: per-token sum of squares partials (512 blocks)
    int kb = bid - 2952;
    int b8 = kb >> 3;
    int cc = kb & 7;
    int s4 = (t & 15) * 4;
    int cg = t >> 4;
    const float* xp = x + (size_t)b8 * 65536 + (size_t)cc * 128 * 64;
    float4 a = {0.f, 0.f, 0.f, 0.f};
#pragma unroll
    for (int j = 0; j < 8; ++j) {
      int c = cg + j * 16;
      float4 v = *(const float4*)(xp + (size_t)c * 64 + s4);
      a.x = fmaf(v.x, v.x, a.x);
      a.y = fmaf(v.y, v.y, a.y);
      a.z = fmaf(v.z, v.z, a.z);
      a.w = fmaf(v.w, v.w, a.w);
    }
    __shared__ float red0[16][68];
    *(float4*)&red0[cg][s4] = a;
    __syncthreads();
    if (t < 64) {
      float s = 0.f;
#pragma unroll
      for (int g = 0; g < 16; ++g) s += red0[g][t];
      ssq8[cc * 4096 + b8 * 64 + t] = s;
    }
  }
}

// ---------------- fused: GEMM0 split-K (blocks 0-287, bf16 partials) + k1 (288-799) ----
__launch_bounds__(512, 4)
__global__ void g0k1(const ushort_t* __restrict__ A, const ushort_t* __restrict__ B,
                     ushort_t* __restrict__ Cb, const float* __restrict__ x,
                     const float* __restrict__ ssq8, __hip_bfloat16* __restrict__ xnb) {
  __shared__ alignas(16) unsigned char SHRAW[65536];
  const int bid = blockIdx.x;
  const int tid = threadIdx.x;
  if (bid >= 288) {
    int ht = tid >> 8, t = tid & 255;
    int tile_id = (bid - 288) * 2 + ht;
    int ct = tile_id & 15, b8 = tile_id >> 4;
    float* tbuf = (float*)(SHRAW + ht * 20480);  // [64][65]
    float* ivs = tbuf + 64 * 65;
    if (t < 64) {
      float s = 0.f;
#pragma unroll
      for (int cc = 0; cc < 8; ++cc) s += ssq8[cc * 4096 + b8 * 64 + t];
      ivs[t] = rsqrtf(fmaxf(s, 1e-24f));
    }
    int s = t & 63, cq = t >> 6;
    const float* xp = x + (size_t)b8 * 65536 + (size_t)ct * 64 * 64;
#pragma unroll
    for (int r = 0; r < 16; ++r) {
      int cl = cq * 16 + r;
      tbuf[cl * 65 + s] = xp[cl * 64 + s];
    }
    __syncthreads();
    int cl = t & 63, sq = t >> 6;
#pragma unroll
    for (int r = 0; r < 16; ++r) {
      int smm = sq * 16 + r;
      int tm = b8 * 64 + smm;
      xnb[(size_t)tm * 1024 + ct * 64 + cl] = __float2bfloat16(tbuf[cl * 65 + smm] * ivs[smm]);
    }
    return;
  }
  ushort_t* SH = (ushort_t*)SHRAW;
  const int Kstride = 2048, N = 1024;
  const int nx = bid & 7, ny = (bid >> 3) % 9, sK = bid / 72;
  const int m0 = ny * 128, n0 = nx * 128;
  const int koff = sK * 512;
  const int w = tid >> 6, l = tid & 63;
  const int wr = w >> 2, wc = w & 3;
  const int srow = w * 8 + (l >> 3);
  const int ksw = ((l & 7) ^ (l >> 3)) * 8;
  const ushort_t* Ag0 = A + (size_t)(m0 + srow) * Kstride + ksw + koff;
  const ushort_t* Ag1 = A + (size_t)(m0 + 64 + srow) * Kstride + ksw + koff;
  const ushort_t* Bg0 = B + (size_t)(n0 + srow) * Kstride + ksw + koff;
  const ushort_t* Bg1 = B + (size_t)(n0 + 64 + srow) * Kstride + ksw + koff;
  const int l0 = w * 512;
  const int l1 = 4096 + w * 512;

  f32x4 acc[4][2];
#pragma unroll
  for (int i = 0; i < 4; ++i)
#pragma unroll
    for (int j = 0; j < 2; ++j) acc[i][j] = (f32x4){0.f, 0.f, 0.f, 0.f};

  const int sw = l & 7, qq = l >> 4;

#define ASH(buf) (SH + (buf)*8192)
#define BSH(buf) (SH + 16384 + (buf)*8192)
#define STAGE(buf, k0)                               \
  {                                                  \
    gload_lds16(Ag0 + (k0), ASH(buf) + l0);          \
    gload_lds16(Ag1 + (k0), ASH(buf) + l1);          \
    gload_lds16(Bg0 + (k0), BSH(buf) + l0);          \
    gload_lds16(Bg1 + (k0), BSH(buf) + l1);          \
  }
#define COMPUTE(buf)                                                                     \
  {                                                                                      \
    s16x8 af[4][2], bf[2][2];                                                            \
    _Pragma("unroll") for (int kk = 0; kk < 2; ++kk) {                                   \
      int slot = (((kk << 2) + qq) ^ sw) * 8;                                            \
      _Pragma("unroll") for (int mi = 0; mi < 4; ++mi)                                   \
          af[mi][kk] = *(const s16x8*)&ASH(buf)[(wr * 64 + mi * 16 + (l & 15)) * 64 +    \
                                               slot];                                   \
      _Pragma("unroll") for (int ni = 0; ni < 2; ++ni)                                   \
          bf[ni][kk] = *(const s16x8*)&BSH(buf)[(wc * 32 + ni * 16 + (l & 15)) * 64 +    \
                                               slot];                                   \
    }                                                                                    \
    _Pragma("unroll") for (int kk = 0; kk < 2; ++kk)                                     \
        _Pragma("unroll") for (int mi = 0; mi < 4; ++mi)                                 \
            _Pragma("unroll") for (int ni = 0; ni < 2; ++ni)                             \
                acc[mi][ni] = __builtin_amdgcn_mfma_f32_16x16x32_bf16(af[mi][kk],        \
                                                                     bf[ni][kk],        \
                                                                     acc[mi][ni], 0, 0, 0); \
  }

  STAGE(0, 0);
  int buf = 0;
  for (int t2 = 0; t2 < 7; ++t2) {
    STAGE(buf ^ 1, (t2 + 1) << 6);
    asm volatile("s_waitcnt vmcnt(4)" ::: "memory");
    __builtin_amdgcn_s_barrier();
    asm volatile("" ::: "memory");
    COMPUTE(buf);
    asm volatile("" ::: "memory");
    __builtin_amdgcn_s_barrier();
    buf ^= 1;
  }
  asm volatile("s_waitcnt vmcnt(0)" ::: "memory");
  __builtin_amdgcn_s_barrier();
  asm volatile("" ::: "memory");
  COMPUTE(buf);
#undef STAGE
#undef COMPUTE
#undef ASH
#undef BSH

  ushort_t* Co = Cb + (size_t)sK * 1152 * 1024;
#pragma unroll
  for (int mi = 0; mi < 4; ++mi) {
    int row = m0 + wr * 64 + mi * 16 + (l >> 4) * 4;
#pragma unroll
    for (int ni = 0; ni < 2; ++ni) {
      int col = n0 + wc * 32 + ni * 16 + (l & 15);
#pragma unroll
      for (int r = 0; r < 4; ++r) {
        __hip_bfloat16 hb = __float2bfloat16(acc[mi][ni][r]);
        Co[(size_t)(row + r) * N + col] = *(ushort_t*)&hb;
      }
    }
  }
}

// ---------------- kpackC: sum 4 bf16 split-K partials -> bf16 stackedA rows 2048+ ----------
__global__ void kpackC(const ushort_t* __restrict__ Wc4b, ushort_t* __restrict__ dst) {
  int i = (blockIdx.x * 256 + threadIdx.x) * 8;
  u16x8 p0 = *(const u16x8*)(Wc4b + i);
  u16x8 p1 = *(const u16x8*)(Wc4b + 1179648 + i);
  u16x8 p2 = *(const u16x8*)(Wc4b + 2359296 + i);
  u16x8 p3 = *(const u16x8*)(Wc4b + 3538944 + i);
  u16x8 o;
#pragma unroll
  for (int j = 0; j < 8; ++j) {
    float s = bf2f(p0[j]) + bf2f(p1[j]) + bf2f(p2[j]) + bf2f(p3[j]);
    __hip_bfloat16 hb = __float2bfloat16(s);
    o[j] = *(ushort_t*)&hb;
  }
  *(u16x8*)(dst + i) = o;
}

// ---------------- big stacked GEMM, 256x256, 8-phase, A+B reg-hold, ONE barrier/phase,
//                  vmcnt(2) coverage (provably race-free), coalesced epilogue ----
__launch_bounds__(512, 2)
__global__ void gemm256_8ph(const ushort_t* __restrict__ A, const ushort_t* __restrict__ B,
                            ushort_t* __restrict__ C, int K, int N) {
  __shared__ alignas(16) ushort_t SH[65536];  // 128 KB
  const int tid = threadIdx.x;
  const int m0 = blockIdx.y * 256, n0 = blockIdx.x * 256;
  const int w = tid >> 6, l = tid & 63;
  const int wr = w >> 2, wc = w & 3;  // 2x4 wave grid; per-wave 128m x 64n
  const int r16 = l & 15, qq = l >> 4, sw = l & 7;
  const int s = tid >> 3;
  const int s_hi = s >> 5, s_lo = s & 31;
  const int ksw = ((tid & 7) ^ (s & 7)) * 8;
  const int NT = K >> 6;

  const ushort_t* pA0 = A + (size_t)(m0 + s) * K + ksw;
  const ushort_t* pA1 = A + (size_t)(m0 + 128 + s) * K + ksw;
  const ushort_t* pB0 = B + (size_t)(n0 + s_hi * 64 + s_lo) * K + ksw;
  const ushort_t* pB1 = B + (size_t)(n0 + 128 + s_hi * 64 + s_lo) * K + ksw;
  ushort_t* dA = SH + tid * 8;
  ushort_t* dB = SH + 32768 + tid * 8;

  f32x4 acc[8][4];
#pragma unroll
  for (int i = 0; i < 8; ++i)
#pragma unroll
    for (int j = 0; j < 4; ++j) acc[i][j] = (f32x4){0.f, 0.f, 0.f, 0.f};

#define SA(kt, h)                                                                        \
  {                                                                                      \
    gload_lds16(pA0 + (size_t)(h) * (K << 6) + ((kt) << 6),                              \
                dA + (((kt)&1) << 14) + ((h) << 13));                                    \
    gload_lds16(pA1 + (size_t)(h) * (K << 6) + ((kt) << 6),                              \
                dA + (((kt)&1) << 14) + ((h) << 13) + 4096);                             \
  }
#define SB(kt, h)                                                                        \
  {                                                                                      \
    gload_lds16(pB0 + (size_t)(h) * (K << 5) + ((kt) << 6),                              \
                dB + (((kt)&1) << 14) + ((h) << 13));                                    \
    gload_lds16(pB1 + (size_t)(h) * (K << 5) + ((kt) << 6),                              \
                dB + (((kt)&1) << 14) + ((h) << 13) + 4096);                             \
  }
#define VMC2 asm volatile("s_waitcnt vmcnt(2)" ::: "memory")
#define VMC0 asm volatile("s_waitcnt vmcnt(0)" ::: "memory")
#define BAR                          \
  asm volatile("" ::: "memory");     \
  __builtin_amdgcn_s_barrier();      \
  asm volatile("" ::: "memory")

#define MFMAQ(mh, nh)                                                                    \
  __builtin_amdgcn_s_setprio(1);                                                         \
  _Pragma("unroll") for (int kk = 0; kk < 2; ++kk)                                       \
      _Pragma("unroll") for (int mi2 = 0; mi2 < 4; ++mi2)                                \
          _Pragma("unroll") for (int ni2 = 0; ni2 < 2; ++ni2)                            \
              acc[(mh)*4 + mi2][(nh)*2 + ni2] = __builtin_amdgcn_mfma_f32_16x16x32_bf16( \
                  af[kk][mi2], bf[kk][(nh)*2 + ni2], acc[(mh)*4 + mi2][(nh)*2 + ni2],    \
                  0, 0, 0);                                                              \
  __builtin_amdgcn_s_setprio(0)

#define KTILE(d, S1, S2, S3, S4, V4)                                                     \
  {                                                                                      \
    s16x8 af[2][4], bf[2][4];                                                            \
    _Pragma("unroll") for (int kk = 0; kk < 2; ++kk) {                                   \
      int slot = (((kk << 2) + qq) ^ sw) * 8;                                            \
      _Pragma("unroll") for (int mi2 = 0; mi2 < 4; ++mi2)                                \
          af[kk][mi2] = *(const s16x8*)&SH[((d) << 14) +                                 \
                                           (wr * 64 + mi2 * 16 + r16) * 64 + slot];      \
      _Pragma("unroll") for (int nh2 = 0; nh2 < 2; ++nh2)                                \
          _Pragma("unroll") for (int ni2 = 0; ni2 < 2; ++ni2)                            \
              bf[kk][nh2 * 2 + ni2] = *(const s16x8*)&SH[32768 + ((d) << 14) +           \
                                           (nh2 << 13) +                                 \
                                           (wc * 32 + ni2 * 16 + r16) * 64 + slot];      \
    }                                                                                    \
    S1; MFMAQ(0, 0); BAR;                                                                \
    S2; MFMAQ(0, 1); BAR;                                                                \
    _Pragma("unroll") for (int kk = 0; kk < 2; ++kk) {                                   \
      int slot = (((kk << 2) + qq) ^ sw) * 8;                                            \
      _Pragma("unroll") for (int mi2 = 0; mi2 < 4; ++mi2)                                \
          af[kk][mi2] = *(const s16x8*)&SH[((d) << 14) + 8192 +                          \
                                           (wr * 64 + mi2 * 16 + r16) * 64 + slot];      \
    }                                                                                    \
    S3; MFMAQ(1, 0); BAR;                                                                \
    S4; MFMAQ(1, 1); V4; BAR;                                                            \
  }

  // prologue: kt0 complete + kt1.{A0,B0}; vmcnt(2) -> kt0's 4 halves landed
  SA(0, 0); SB(0, 0); SA(0, 1); SB(0, 1); SA(1, 0); SB(1, 0);
  VMC2;
  __builtin_amdgcn_s_barrier();
  asm volatile("" ::: "memory");

#pragma unroll 1
  for (int I = 0; I < (NT >> 1) - 1; ++I) {
    const int kt = 2 * I;
    const int k1 = kt + 1, k2 = kt + 2, k3 = kt + 3;
    KTILE(0, SA(k1, 1), SB(k1, 1), SA(k2, 0), SB(k2, 0), VMC2);
    KTILE(1, SA(k2, 1), SB(k2, 1), SA(k3, 0), SB(k3, 0), VMC2);
  }
  // peeled last K-pair (kt = NT-2): vmcnt(0) before consuming the final half-tiles
  {
    const int k1 = NT - 1;
    KTILE(0, SA(k1, 1), SB(k1, 1), , , VMC0);
    KTILE(1, , , , , );
  }
#undef KTILE
#undef MFMAQ
#undef BAR
#undef SA
#undef SB
#undef VMC2
#undef VMC0

  // coalesced epilogue: per-wave LDS bounce, u16x8 stores
  ushort_t* eb = SH + w * 2048;
  const int erow = (l >> 4) * 4;
  const int rrow = l >> 2, rc = (l & 3) * 16;
#pragma unroll
  for (int mi = 0; mi < 8; ++mi) {
    asm volatile("s_waitcnt lgkmcnt(0)" ::: "memory");
#pragma unroll
    for (int ni = 0; ni < 4; ++ni)
#pragma unroll
      for (int r = 0; r < 4; ++r) {
        __hip_bfloat16 hb = __float2bfloat16(acc[mi][ni][r]);
        eb[(erow + r) * 68 + ni * 16 + r16] = *(ushort_t*)&hb;
      }
    asm volatile("s_waitcnt lgkmcnt(0)" ::: "memory");
    u16x8 v0 = *(const u16x8*)&eb[rrow * 68 + rc];
    u16x8 v1 = *(const u16x8*)&eb[rrow * 68 + rc + 8];
    size_t gbase = (size_t)(m0 + wr * 128 + mi * 16 + rrow) * N + n0 + wc * 64 + rc;
    *(u16x8*)&C[gbase] = v0;
    *(u16x8*)&C[gbase + 8] = v1;
  }
}

// ---------------- K5: row softmax over tokens + gate sigmoid, one wave per (q,b) ----------------
__launch_bounds__(256)
__global__ void k5_softmax(const ushort_t* __restrict__ logitsTb, const float* __restrict__ bWg,
                           float* __restrict__ colsumW, ushort_t* __restrict__ wbT) {
  int wv = (blockIdx.x << 2) + (threadIdx.x >> 6);
  int q = wv >> 3, b = wv & 7;
  int l = threadIdx.x & 63;
  int g = q >> 7;
  size_t base = (size_t)q * 4096 + b * 512 + l * 8;
  u16x8 v8 = *(const u16x8*)(logitsTb + base);
  float vs[8];
#pragma unroll
  for (int i = 0; i < 8; ++i) vs[i] = bf2f(v8[i]);
  float M = vs[0];
#pragma unroll
  for (int i = 1; i < 8; ++i) M = fmaxf(M, vs[i]);
#pragma unroll
  for (int m = 1; m < 64; m <<= 1) M = fmaxf(M, __shfl_xor(M, m, 64));
  float e[8], S = 0.f;
#pragma unroll
  for (int i = 0; i < 8; ++i) {
    e[i] = expf(vs[i] - M);
    S += e[i];
  }
#pragma unroll
  for (int m = 1; m < 64; m <<= 1) S += __shfl_xor(S, m, 64);
  float R = 1.0f / S;
  u16x8 g8 = *(const u16x8*)(logitsTb + (size_t)(1024 + g) * 4096 + b * 512 + l * 8);
  float bg = bWg[g];
  float wv8[8], wsum = 0.f;
#pragma unroll
  for (int i = 0; i < 8; ++i) {
    float gl = bf2f(g8[i]);
    float ag = 1.0f / (1.0f + expf(-(gl + bg)));
    wv8[i] = e[i] * R * ag;
    wsum += wv8[i];
  }
#pragma unroll
  for (int m = 1; m < 64; m <<= 1) wsum += __shfl_xor(wsum, m, 64);
  if (l == 0) colsumW[b * 1024 + q] = wsum;
  u16x8 o;
#pragma unroll
  for (int i = 0; i < 8; ++i) {
    __hip_bfloat16 hb = __float2bfloat16(wv8[i]);
    o[i] = *(ushort_t*)&hb;
  }
  *(u16x8*)(wbT + base) = o;
}

// ---------------- K6: VLAD einsum via MFMA, 64x64 tile, BK=128 (2 g's/step, 4 steps) ----
__launch_bounds__(256)
__global__ void k6_vlad_mfma(const ushort_t* __restrict__ wbT, const ushort_t* __restrict__ YcT,
                             float* __restrict__ vpart) {
  int kt = blockIdx.x >> 2, dt = blockIdx.x & 3;
  int ms = blockIdx.y, b = blockIdx.z;
  __shared__ alignas(16) ushort_t Ash[2][8192];  // [buf][2 g][64 r][64 tok]
  __shared__ alignas(16) ushort_t Bsh[2][8192];
  const int tid = threadIdx.x;
  const int w = tid >> 6, l = tid & 63;
  const int wr = w >> 1, wc = w & 1;
  const int crow = l >> 3;
  const int ksw = ((l & 7) ^ crow) * 8;

  const ushort_t* Ap[2];
  const ushort_t* Bp[2];
  int loff[2];
#pragma unroll
  for (int c = 0; c < 2; ++c) {
    int chunk = w * 2 + c;
    Ap[c] = wbT + (size_t)(kt * 64 + chunk * 8 + crow) * 4096 + b * 512 + ms * 64 + ksw;
    Bp[c] = YcT + (size_t)(dt * 64 + chunk * 8 + crow) * 4096 + b * 512 + ms * 64 + ksw;
    loff[c] = chunk * 512;
  }

  f32x4 acc[2][2];
#pragma unroll
  for (int i = 0; i < 2; ++i)
#pragma unroll
    for (int j = 0; j < 2; ++j) acc[i][j] = (f32x4){0.f, 0.f, 0.f, 0.f};

  const int sw = l & 7, qq = l >> 4;

// stage g-pair p = {2p, 2p+1}: 8 gload_lds (A: g-stride 128 rows=524288; B: 256 rows=1048576)
#define STAGE6(buf, p)                                                       \
  {                                                                          \
    size_t gA0 = (size_t)(2 * (p)) * 524288, gA1 = gA0 + 524288;             \
    size_t gB0 = (size_t)(2 * (p)) * 1048576, gB1 = gB0 + 1048576;           \
    gload_lds16(Ap[0] + gA0, &Ash[buf][loff[0]]);                            \
    gload_lds16(Ap[1] + gA0, &Ash[buf][loff[1]]);                            \
    gload_lds16(Ap[0] + gA1, &Ash[buf][4096 + loff[0]]);                     \
    gload_lds16(Ap[1] + gA1, &Ash[buf][4096 + loff[1]]);                     \
    gload_lds16(Bp[0] + gB0, &Bsh[buf][loff[0]]);                            \
    gload_lds16(Bp[1] + gB0, &Bsh[buf][loff[1]]);                            \
    gload_lds16(Bp[0] + gB1, &Bsh[buf][4096 + loff[0]]);                     \
    gload_lds16(Bp[1] + gB1, &Bsh[buf][4096 + loff[1]]);                     \
  }
#define COMPUTE6(buf)                                                                    \
  _Pragma("unroll") for (int gg = 0; gg < 2; ++gg) {                                     \
    s16x8 af[2][2], bf[2][2];                                                            \
    _Pragma("unroll") for (int kk = 0; kk < 2; ++kk) {                                   \
      int slot = (((kk << 2) + qq) ^ sw) * 8;                                            \
      _Pragma("unroll") for (int mi = 0; mi < 2; ++mi) {                                 \
        af[mi][kk] = *(const s16x8*)&Ash[buf][gg * 4096 +                                \
                                             (wr * 32 + mi * 16 + (l & 15)) * 64 +      \
                                             slot];                                     \
        bf[mi][kk] = *(const s16x8*)&Bsh[buf][gg * 4096 +                                \
                                             (wc * 32 + mi * 16 + (l & 15)) * 64 +      \
                                             slot];                                     \
      }                                                                                  \
    }                                                                                    \
    _Pragma("unroll") for (int kk = 0; kk < 2; ++kk)                                     \
        _Pragma("unroll") for (int mi = 0; mi < 2; ++mi)                                 \
            _Pragma("unroll") for (int ni = 0; ni < 2; ++ni)                             \
                acc[mi][ni] = __builtin_amdgcn_mfma_f32_16x16x32_bf16(af[mi][kk],        \
                                                                     bf[ni][kk],        \
                                                                     acc[mi][ni], 0, 0, 0); \
  }

  STAGE6(0, 0);
  int buf = 0;
  for (int p = 0; p < 3; ++p) {  // 4 steps total (g-pairs)
    STAGE6(buf ^ 1, p + 1);
    asm volatile("s_waitcnt vmcnt(8)" ::: "memory");
    __builtin_amdgcn_s_barrier();
    asm volatile("" ::: "memory");
    COMPUTE6(buf);
    asm volatile("" ::: "memory");
    __builtin_amdgcn_s_barrier();
    buf ^= 1;
  }
  asm volatile("s_waitcnt vmcnt(0)" ::: "memory");
  __builtin_amdgcn_s_barrier();
  asm volatile("" ::: "memory");
  COMPUTE6(buf);
#undef STAGE6
#undef COMPUTE6

#pragma unroll
  for (int mi = 0; mi < 2; ++mi) {
    int row = kt * 64 + wr * 32 + mi * 16 + (l >> 4) * 4;
#pragma unroll
    for (int ni = 0; ni < 2; ++ni) {
      int col = dt * 64 + wc * 32 + ni * 16 + (l & 15);
#pragma unroll
      for (int r = 0; r < 4; ++r)
        vpart[((size_t)(ms * 8 + b) * 128 + row + r) * 256 + col] = acc[mi][ni][r];
    }
  }
}

// ---------------- K7: combine 8 partials + bias-part - S*centroid, intra-normalize ----------------
__global__ void k7_intranorm(const float* __restrict__ vpart, const float* __restrict__ colsumW,
                             const float* __restrict__ b_inp, const float* __restrict__ cent,
                             float* __restrict__ out, float* __restrict__ ss1) {
  int k = blockIdx.x;
  int b = blockIdx.y;
  int d = threadIdx.x;
  float S = 0.f, bp = 0.f;
#pragma unroll
  for (int g = 0; g < 8; ++g) {
    float cw = colsumW[b * 1024 + g * 128 + k];
    S += cw;
    bp = fmaf(b_inp[g * 256 + d], cw, bp);
  }
  size_t off = ((size_t)b * 128 + k) * 256 + d;
  float v = bp - S * cent[(size_t)k * 256 + d];
#pragma unroll
  for (int i = 0; i < 8; ++i) v += vpart[off + (size_t)i * 262144];
  float ss = v * v;
#pragma unroll
  for (int m = 1; m < 64; m <<= 1) ss += __shfl_xor(ss, m, 64);
  __shared__ float red[4];
  int lane = d & 63, wv = d >> 6;
  if (lane == 0) red[wv] = ss;
  __syncthreads();
  float tot = red[0] + red[1] + red[2] + red[3];
  float rinv = 1.0f / fmaxf(sqrtf(tot), EPSN);
  out[off] = v * rinv;
  if (d == 0) ss1[b * 128 + k] = tot * rinv * rinv;
}

// ---------------- K8: final global L2 norm ----------------
__global__ void k8_finalnorm(const float* __restrict__ ss1, float* __restrict__ out) {
  int b = blockIdx.x;
  int t = threadIdx.x;
  __shared__ float red[256];
  red[t] = (t < 128) ? ss1[b * 128 + t] : 0.f;
  __syncthreads();
  for (int o = 128; o > 0; o >>= 1) {
    if (t < o) red[t] += red[t + o];
    __syncthreads();
  }
  float rinv = 1.0f / fmaxf(sqrtf(red[0]), EPSN);
  float* op = out + (size_t)b * 32768;
  for (int i = t; i < 32768; i += 256) op[i] *= rinv;
}

extern "C" void kernel_launch(void* const* d_in, const int* in_sizes, int n_in,
                              void* d_out, int out_size, void* d_ws, size_t ws_size,
                              hipStream_t stream) {
  const float* x     = (const float*)d_in[0];
  const float* W_inp = (const float*)d_in[1];
  const float* b_inp = (const float*)d_in[2];
  const float* W_g   = (const float*)d_in[3];
  const float* b_g   = (const float*)d_in[4];
  const float* W_gk  = (const float*)d_in[5];
  // b_gk (d_in[6]) cancels in the token-axis softmax — unused.
  const float* cent  = (const float*)d_in[7];
  float* out = (float*)d_out;
  float* ws = (float*)d_ws;

  // workspace layout (float offsets), total 12,887,104 floats = 51.5 MB
  float* ssq8    = ws + 0;         // 32768
  float* colsumW = ws + 32768;     // 8192
  float* ss1     = ws + 40960;     // 1024
  float* bWg     = ws + 41984;     // 64
  ushort_t* xnb  = (ushort_t*)(ws + 42048);        // [4096][1024] bf16 (2097152 fl)
  ushort_t* wbT  = xnb;                            // alias (xnb dead after gemm256)
  ushort_t* stackedA = (ushort_t*)(ws + 2139200);  // [3328][1024] bf16 (1703936 fl)
  ushort_t* WibT = (ushort_t*)(ws + 3843136);      // [1024][2048] bf16 (1048576 fl)
  ushort_t* Wgkx = (ushort_t*)(ws + 4891712);      // [1152][2048] bf16 (1179648 fl)
  float* vpart   = ws + 3843136;   // 2097152 fl, aliases WibT+Wgkx (dead after gemm0)
  ushort_t* Wc4b = (ushort_t*)(ws + 6071360);      // [4][1152][1024] bf16, dead after kpackC
  ushort_t* Cstacked = (ushort_t*)(ws + 6071360);  // [3328][4096] bf16 (6815744 fl), over Wc4b
  ushort_t* YcT      = Cstacked;                   // rows 0-2047
  ushort_t* logitsTb = Cstacked + (size_t)2048 * 4096;  // rows 2048-3199

  // fused prep: Wgkx pack + gate + bWg + Wib/WibT dual + pad + k0 ssq partials
  kpack2<<<3464, 256, 0, stream>>>(W_inp, W_gk, W_g, b_inp, b_g,
                                   (__hip_bfloat16*)stackedA, (__hip_bfloat16*)Wgkx, WibT, bWg,
                                   x, ssq8);
  // fused: gemm0 split-K x4 (bf16 partials, blocks 0-287) || k1 transpose (288-799)
  g0k1<<<800, 512, 0, stream>>>(Wgkx, WibT, Wc4b, x, ssq8, (__hip_bfloat16*)xnb);
  // pack: stackedA rows 2048-3199 = bf16(sum_s Wc4b[s])
  kpackC<<<576, 256, 0, stream>>>(Wc4b, stackedA + (size_t)2048 * 1024);
  // big stacked GEMM (256^2, 8-phase, 1 barrier/phase, vmcnt(2)): Cstacked = stackedA @ xnb^T
  gemm256_8ph<<<dim3(16, 13), 512, 0, stream>>>(stackedA, xnb, Cstacked, 1024, 4096);
  k5_softmax<<<2048, 256, 0, stream>>>(logitsTb, bWg, colsumW, wbT);
  k6_vlad_mfma<<<dim3(8, 8, 8), 256, 0, stream>>>(wbT, YcT, vpart);
  k7_intranorm<<<dim3(128, 8), 256, 0, stream>>>(vpart, colsumW, b_inp, cent, out, ss1);
  k8_finalnorm<<<8, 256, 0, stream>>>(ss1, out);
}